// Round 1
// baseline (1136.309 us; speedup 1.0000x reference)
//
#include <hip/hip_runtime.h>

// Problem constants (from reference)
#define B_    256
#define A_    100
#define NB_   10
#define BOND_ 110
#define AF_   82
#define BF_   6
#define H_    300
#define MA_   (B_ * A_)     // 25600 atom rows
#define MB_   (B_ * BOND_)  // 28160 bond rows

// ---------------------------------------------------------------------------
// Generic fp32 tiled GEMM: C[M,300] = epi( A[M,K1]@W1 (+ A2[M,K2]@W2) + bias )
// BM=64, BN=64, BK=16; 256 threads; 4x4 accumulator per thread.
// Epilogue options: bias add, relu, elementwise-mul by E, row mask by n_atoms.
// ---------------------------------------------------------------------------
template<bool DUAL, bool BIAS, bool RELU, bool EPIMUL, bool ROWMASK>
__global__ __launch_bounds__(256) void gemm_k(
    const float* __restrict__ A,  int K1,
    const float* __restrict__ A2, int K2,
    const float* __restrict__ W1,
    const float* __restrict__ W2,
    const float* __restrict__ bias,
    const float* __restrict__ E,
    const int*   __restrict__ n_atoms,
    float* __restrict__ C, int M)
{
    constexpr int BM = 64, BN = 64, BK = 16;
    __shared__ float sA[BK][BM + 4];   // k-major, pad 4 floats: 16B-aligned rows, <=2-way bank alias
    __shared__ float sW[BK][BN + 4];

    const int tid = threadIdx.x;
    const int tx  = tid & 15;          // output col group
    const int ty  = tid >> 4;          // output row group
    const int m0  = blockIdx.x * BM;
    const int n0  = blockIdx.y * BN;

    float acc[4][4] = {};

    const int npass = DUAL ? 2 : 1;
    for (int pass = 0; pass < npass; ++pass) {
        const float* Ap = (DUAL && pass) ? A2 : A;
        const float* Wp = (DUAL && pass) ? W2 : W1;
        const int    K  = (DUAL && pass) ? K2 : K1;

        for (int k0 = 0; k0 < K; k0 += BK) {
            // Load A tile: 64 rows x 16 k  (lane-contiguous in k -> 64B/row segments)
            {
                const int m = tid >> 4;      // 0..15
                const int k = tid & 15;      // 0..15
                const int kk = k0 + k;
                #pragma unroll
                for (int r = 0; r < 4; ++r) {
                    const int mm = m + r * 16;
                    float v = 0.f;
                    if (kk < K) v = Ap[(size_t)(m0 + mm) * K + kk];
                    sA[k][mm] = v;
                }
            }
            // Load W tile: 16 k x 64 n (lane-contiguous in n -> 256B segments)
            {
                const int kb = tid >> 6;     // 0..3
                const int n  = tid & 63;     // 0..63
                const int nn = n0 + n;
                #pragma unroll
                for (int r = 0; r < 4; ++r) {
                    const int kk0 = kb + r * 4;
                    const int kk  = k0 + kk0;
                    float v = 0.f;
                    if (kk < K && nn < H_) v = Wp[(size_t)kk * H_ + nn];
                    sW[kk0][n] = v;
                }
            }
            __syncthreads();

            #pragma unroll
            for (int k = 0; k < BK; ++k) {
                float a[4], w[4];
                #pragma unroll
                for (int i = 0; i < 4; ++i) a[i] = sA[k][ty * 4 + i];  // ds_read_b128 (16B aligned)
                #pragma unroll
                for (int j = 0; j < 4; ++j) w[j] = sW[k][tx * 4 + j];  // ds_read_b128
                #pragma unroll
                for (int i = 0; i < 4; ++i)
                    #pragma unroll
                    for (int j = 0; j < 4; ++j)
                        acc[i][j] = fmaf(a[i], w[j], acc[i][j]);
            }
            __syncthreads();
        }
    }

    // Epilogue
    #pragma unroll
    for (int i = 0; i < 4; ++i) {
        const int row = m0 + ty * 4 + i;
        if (row >= M) continue;
        bool rowvalid = true;
        if (ROWMASK) rowvalid = ((row % A_) < n_atoms[row / A_]);
        #pragma unroll
        for (int j = 0; j < 4; ++j) {
            const int col = n0 + tx * 4 + j;
            if (col >= H_) continue;
            float v = acc[i][j];
            if (BIAS)   v += bias[col];
            if (RELU)   v  = fmaxf(v, 0.f);
            if (EPIMUL) v *= E[(size_t)row * H_ + col];
            if (ROWMASK && !rowvalid) v = 0.f;
            C[(size_t)row * H_ + col] = v;
        }
    }
}

// ---------------------------------------------------------------------------
// Aggregation for depth 0/1:
//   nei[ba, c] = sum_{n < num_nbs[ba]} relu( hw[arow(n), c] + bwn[brow(n), c] )
// (b_nei is pre-folded into bwn.)
// ---------------------------------------------------------------------------
__global__ __launch_bounds__(256) void agg_relu_k(
    const float* __restrict__ hw,       // [MA_, H]
    const float* __restrict__ bwn,      // [MB_, H], includes b_nei
    const int*   __restrict__ ag,       // [B,A,NB,2]
    const int*   __restrict__ bg,       // [B,A,NB,2]
    const int*   __restrict__ num_nbs,  // [B,A]
    float* __restrict__ nei)            // [MA_, H]
{
    const size_t e = (size_t)blockIdx.x * blockDim.x + threadIdx.x;
    const size_t total = (size_t)MA_ * H_;
    if (e >= total) return;
    const int c  = (int)(e % H_);
    const int ba = (int)(e / H_);
    const int nn = num_nbs[ba];
    const int* agp = ag + (size_t)ba * NB_ * 2;
    const int* bgp = bg + (size_t)ba * NB_ * 2;
    float s = 0.f;
    for (int n = 0; n < nn; ++n) {
        const int arow = agp[2 * n] * A_    + agp[2 * n + 1];
        const int brow = bgp[2 * n] * BOND_ + bgp[2 * n + 1];
        const float v = hw[(size_t)arow * H_ + c] + bwn[(size_t)brow * H_ + c];
        s += fmaxf(v, 0.f);
    }
    nei[e] = s;
}

// ---------------------------------------------------------------------------
// Aggregation for the last depth:
//   nei[ba, c] = sum_{n < num_nbs[ba]} hw2[arow(n), c] * bw2[brow(n), c]
// ---------------------------------------------------------------------------
__global__ __launch_bounds__(256) void agg_prod_k(
    const float* __restrict__ hw2,      // [MA_, H] = h @ w2a
    const float* __restrict__ bw2,      // [MB_, H] = bond_feats @ w2b
    const int*   __restrict__ ag,
    const int*   __restrict__ bg,
    const int*   __restrict__ num_nbs,
    float* __restrict__ nei)
{
    const size_t e = (size_t)blockIdx.x * blockDim.x + threadIdx.x;
    const size_t total = (size_t)MA_ * H_;
    if (e >= total) return;
    const int c  = (int)(e % H_);
    const int ba = (int)(e / H_);
    const int nn = num_nbs[ba];
    const int* agp = ag + (size_t)ba * NB_ * 2;
    const int* bgp = bg + (size_t)ba * NB_ * 2;
    float s = 0.f;
    for (int n = 0; n < nn; ++n) {
        const int arow = agp[2 * n] * A_    + agp[2 * n + 1];
        const int brow = bgp[2 * n] * BOND_ + bgp[2 * n + 1];
        s += hw2[(size_t)arow * H_ + c] * bw2[(size_t)brow * H_ + c];
    }
    nei[e] = s;
}

// ---------------------------------------------------------------------------
extern "C" void kernel_launch(void* const* d_in, const int* in_sizes, int n_in,
                              void* d_out, int out_size, void* d_ws, size_t ws_size,
                              hipStream_t stream)
{
    const float* atom_feats = (const float*)d_in[0];   // [B,A,AF]
    const float* bond_feats = (const float*)d_in[1];   // [B,BOND,BF]
    const float* w_fc1      = (const float*)d_in[2];   // [AF,H]
    const float* w_nei      = (const float*)d_in[3];   // [H+BF,H]
    const float* b_nei      = (const float*)d_in[4];   // [H]
    const float* w_atom     = (const float*)d_in[5];   // [2H,H]
    const float* b_atom     = (const float*)d_in[6];   // [H]
    const float* w2a        = (const float*)d_in[7];   // [H,H]
    const float* w2b        = (const float*)d_in[8];   // [BF,H]
    const float* w_fc2      = (const float*)d_in[9];   // [H,H]
    const int*   atom_graph = (const int*)d_in[10];    // [B,A,NB,2]
    const int*   bond_graph = (const int*)d_in[11];    // [B,A,NB,2]
    const int*   num_nbs    = (const int*)d_in[12];    // [B,A]
    const int*   n_atoms    = (const int*)d_in[13];    // [B]
    float* out = (float*)d_out;

    // Workspace layout (all fp32 rows of H=300):
    //   bufX [MA_,H] : h (ping)
    //   bufY [MA_,H] : hw / h_new (pong)
    //   bufZ [MA_,H] : nei
    //   bufW [MB_,H] : bond transform (bwn then bw2)
    const size_t SZ_A = (size_t)MA_ * H_ * sizeof(float);  // 30.72 MB
    char* ws = (char*)d_ws;
    float* bufX = (float*)(ws);
    float* bufY = (float*)(ws + SZ_A);
    float* bufZ = (float*)(ws + 2 * SZ_A);
    float* bufW = (float*)(ws + 3 * SZ_A);
    (void)ws_size; (void)in_sizes; (void)n_in; (void)out_size;

    const dim3 blk(256);
    const dim3 gridA(MA_ / 64, 5);   // 400 x 5
    const dim3 gridB(MB_ / 64, 5);   // 440 x 5
    const int  aggBlocks = (MA_ * H_ + 255) / 256;

    // h = relu(atom_feats @ w_fc1)
    gemm_k<false, false, true, false, false><<<gridA, blk, 0, stream>>>(
        atom_feats, AF_, nullptr, 0, w_fc1, nullptr, nullptr, nullptr, nullptr, bufX, MA_);

    // bwn = bond_feats @ w_nei[H:,:] + b_nei   (gather-commuted bond transform)
    gemm_k<false, true, false, false, false><<<gridB, blk, 0, stream>>>(
        bond_feats, BF_, nullptr, 0, w_nei + (size_t)H_ * H_, nullptr, b_nei, nullptr, nullptr, bufW, MB_);

    float* hcur = bufX;
    float* hnew = bufY;
    for (int it = 0; it < 2; ++it) {
        // hw = hcur @ w_nei[:H,:]
        gemm_k<false, false, false, false, false><<<gridA, blk, 0, stream>>>(
            hcur, H_, nullptr, 0, w_nei, nullptr, nullptr, nullptr, nullptr, hnew, MA_);
        // nei = masked-sum relu(gather(hw) + gather(bwn))
        agg_relu_k<<<aggBlocks, blk, 0, stream>>>(hnew, bufW, atom_graph, bond_graph, num_nbs, bufZ);
        // h_new = relu(hcur @ w_atom[:H] + nei @ w_atom[H:] + b_atom)   (overwrites hw)
        gemm_k<true, true, true, false, false><<<gridA, blk, 0, stream>>>(
            hcur, H_, bufZ, H_, w_atom, w_atom + (size_t)H_ * H_, b_atom, nullptr, nullptr, hnew, MA_);
        // swap ping-pong
        float* t = hcur; hcur = hnew; hnew = t;
    }

    // bw2 = bond_feats @ w2b   (reuse bond buffer)
    gemm_k<false, false, false, false, false><<<gridB, blk, 0, stream>>>(
        bond_feats, BF_, nullptr, 0, w2b, nullptr, nullptr, nullptr, nullptr, bufW, MB_);

    // hw2 = h @ w2a
    gemm_k<false, false, false, false, false><<<gridA, blk, 0, stream>>>(
        hcur, H_, nullptr, 0, w2a, nullptr, nullptr, nullptr, nullptr, hnew, MA_);

    // nei = masked-sum gather(hw2) * gather(bw2)
    agg_prod_k<<<aggBlocks, blk, 0, stream>>>(hnew, bufW, atom_graph, bond_graph, num_nbs, bufZ);

    // local = (h @ w_fc2) * nei, masked by n_atoms
    gemm_k<false, false, false, true, true><<<gridA, blk, 0, stream>>>(
        hcur, H_, nullptr, 0, w_fc2, nullptr, nullptr, bufZ, n_atoms, out, MA_);
}

// Round 2
// 500.410 us; speedup vs baseline: 2.2708x; 2.2708x over previous
//
#include <hip/hip_runtime.h>

// Problem constants
#define B_    256
#define A_    100
#define NB_   10
#define BOND_ 110
#define AF_   82
#define BF_   6
#define H_    300
#define NP_   320           // padded H
#define MA_   (B_ * A_)     // 25600
#define MB_   (B_ * BOND_)  // 28160
#define KP300 320
#define KP82  96

typedef __attribute__((ext_vector_type(8))) short short8;
typedef __attribute__((ext_vector_type(4))) float f32x4;

// ---- bf16 helpers (RNE via bit trick) ----
__device__ __forceinline__ ushort f2bf(float v) {
    union { float f; unsigned u; } x; x.f = v;
    unsigned r = x.u + 0x7fffu + ((x.u >> 16) & 1u);
    return (ushort)(r >> 16);
}
__device__ __forceinline__ float bf2f(ushort h) {
    union { float f; unsigned u; } x; x.u = ((unsigned)h) << 16;
    return x.f;
}

// ---- async global->LDS, 16B per lane ----
__device__ __forceinline__ void gload16(const void* g, void* l) {
    __builtin_amdgcn_global_load_lds(
        (const __attribute__((address_space(1))) void*)g,
        (__attribute__((address_space(3))) void*)l, 16, 0, 0);
}

// ===========================================================================
// MFMA GEMM, split-bf16 (3-term) : C[M,320] = epi( A@W (+ A2@W2) )
// A arrays: [M][KP] bf16 hi/lo.  W arrays: transposed [320][KP] bf16 hi/lo.
// BM=64, BN=320(full), BK=32. 256 threads = 4 waves, wave w owns cols [80w,80w+80).
// LDS granule map (16B granules, linear): Ah[0,320) Al[320,640) Bh[640,2240) Bl[2240,3840)
// Row pitch 80B (5 granules: 4 data + 1 dead) -> 2-way-only bank aliasing on ds_read_b128.
// OUTMODE: 0=SPLIT(hi/lo bf16, padded), 1=F32 padded, 2=FINAL(*E, rowmask, [M][300])
// ===========================================================================
template<bool DUAL, bool BIAS, bool RELU, int OUTMODE>
__global__ __launch_bounds__(256, 2) void mgemm_k(
    const ushort* __restrict__ aH, const ushort* __restrict__ aL,
    const ushort* __restrict__ wH, const ushort* __restrict__ wL,
    const ushort* __restrict__ aH2, const ushort* __restrict__ aL2,
    const ushort* __restrict__ wH2, const ushort* __restrict__ wL2,
    int KP,
    const float* __restrict__ bias,
    const float* __restrict__ E,
    const int*   __restrict__ n_atoms,
    ushort* __restrict__ oHi, ushort* __restrict__ oLo,
    float*  __restrict__ oF)
{
    __shared__ ushort lds[3840 * 8];          // 61440 B
    const int tid  = threadIdx.x;
    const int m0   = blockIdx.x * 64;
    const int lane = tid & 63;
    const int l16  = lane & 15;
    const int kg   = lane >> 4;
    const int w    = tid >> 6;

    // per-call (q=0..14) granule decode: G = q*256 + tid
    int sel[15]; int off[15];
    #pragma unroll
    for (int q = 0; q < 15; ++q) {
        int G = q * 256 + tid;
        int s, local;
        if      (G < 320)  { s = 0; local = G; }
        else if (G < 640)  { s = 1; local = G - 320; }
        else if (G < 2240) { s = 2; local = G - 640; }
        else               { s = 3; local = G - 2240; }
        int rc = local / 5;
        int ch = local % 5; if (ch == 4) ch = 3;      // dead pad granule: duplicate
        int rowterm = (s < 2) ? (m0 + rc) : rc;
        sel[q] = s;
        off[q] = rowterm * KP * 2 + ch * 16;          // byte offset (k0 added later)
    }
    char* ldst = (char*)&lds[0] + ((tid & 192) << 4); // wave-uniform dest base

    f32x4 acc[4][5] = {};
    const int aoff = l16 * 80 + kg * 16;
    const int boff = (w * 80 + l16) * 80 + kg * 16;

    const int npass = DUAL ? 2 : 1;
    for (int pass = 0; pass < npass; ++pass) {
        const ushort* s0 = (DUAL && pass) ? aH2 : aH;
        const ushort* s1 = (DUAL && pass) ? aL2 : aL;
        const ushort* s2 = (DUAL && pass) ? wH2 : wH;
        const ushort* s3 = (DUAL && pass) ? wL2 : wL;
        const char* ptr[15];
        #pragma unroll
        for (int q = 0; q < 15; ++q) {
            const ushort* b = (sel[q] == 0) ? s0 : (sel[q] == 1) ? s1 : (sel[q] == 2) ? s2 : s3;
            ptr[q] = (const char*)b + off[q];
        }
        const int ksteps = KP >> 5;
        for (int ks = 0; ks < ksteps; ++ks) {
            __syncthreads();
            #pragma unroll
            for (int q = 0; q < 15; ++q) gload16(ptr[q], ldst + q * 4096);
            __syncthreads();

            short8 ah[4], al[4];
            #pragma unroll
            for (int rt = 0; rt < 4; ++rt) {
                ah[rt] = *(const short8*)((const char*)lds +     0 + aoff + rt * 1280);
                al[rt] = *(const short8*)((const char*)lds +  5120 + aoff + rt * 1280);
            }
            #pragma unroll
            for (int c = 0; c < 5; ++c) {
                short8 bh = *(const short8*)((const char*)lds + 10240 + boff + c * 1280);
                short8 bl = *(const short8*)((const char*)lds + 35840 + boff + c * 1280);
                #pragma unroll
                for (int rt = 0; rt < 4; ++rt) {
                    acc[rt][c] = __builtin_amdgcn_mfma_f32_16x16x32_bf16(ah[rt], bh, acc[rt][c], 0, 0, 0);
                    acc[rt][c] = __builtin_amdgcn_mfma_f32_16x16x32_bf16(al[rt], bh, acc[rt][c], 0, 0, 0);
                    acc[rt][c] = __builtin_amdgcn_mfma_f32_16x16x32_bf16(ah[rt], bl, acc[rt][c], 0, 0, 0);
                }
            }
            #pragma unroll
            for (int q = 0; q < 15; ++q) ptr[q] += 64;
        }
    }

    // epilogue  (C/D map: col = l16 (+16c+80w), row = kg*4 + reg (+16rt))
    float biasv[5];
    #pragma unroll
    for (int c = 0; c < 5; ++c) {
        int col = w * 80 + c * 16 + l16;
        biasv[c] = (BIAS && col < H_) ? bias[col] : 0.f;
    }
    #pragma unroll
    for (int rt = 0; rt < 4; ++rt) {
        #pragma unroll
        for (int c = 0; c < 5; ++c) {
            const int col = w * 80 + c * 16 + l16;
            #pragma unroll
            for (int r = 0; r < 4; ++r) {
                const int row = m0 + rt * 16 + kg * 4 + r;
                float v = acc[rt][c][r];
                if (BIAS) v += biasv[c];
                if (RELU) v = fmaxf(v, 0.f);
                if (OUTMODE == 0) {
                    ushort hi = f2bf(v);
                    ushort lo = f2bf(v - bf2f(hi));
                    size_t o = (size_t)row * NP_ + col;
                    oHi[o] = hi; oLo[o] = lo;
                } else if (OUTMODE == 1) {
                    oF[(size_t)row * NP_ + col] = v;
                } else {
                    if (col < H_) {
                        v *= E[(size_t)row * NP_ + col];
                        int b = row / A_;
                        int a = row - b * A_;
                        if (a >= n_atoms[b]) v = 0.f;
                        oF[(size_t)row * H_ + col] = v;
                    }
                }
            }
        }
    }
}

// ---------------------------------------------------------------------------
// Weight transpose + split + pad: src [K][300] f32 -> dst [320][KP] bf16 hi/lo
// ---------------------------------------------------------------------------
__global__ __launch_bounds__(256) void conv_w_k(
    const float* __restrict__ src, int K, int KP,
    ushort* __restrict__ dhi, ushort* __restrict__ dlo)
{
    int idx = blockIdx.x * 256 + threadIdx.x;
    if (idx >= NP_ * KP) return;
    int c = idx / KP, k = idx - c * KP;
    float v = (c < H_ && k < K) ? src[(size_t)k * H_ + c] : 0.f;
    ushort hi = f2bf(v);
    dhi[idx] = hi;
    dlo[idx] = f2bf(v - bf2f(hi));
}

// atom_feats [M][82] f32 -> [M][96] bf16 hi/lo (zero-padded)
__global__ __launch_bounds__(256) void conv_af_k(
    const float* __restrict__ src, ushort* __restrict__ dhi, ushort* __restrict__ dlo)
{
    int idx = blockIdx.x * 256 + threadIdx.x;
    if (idx >= MA_ * KP82) return;
    int row = idx / KP82, k = idx - row * KP82;
    float v = (k < AF_) ? src[(size_t)row * AF_ + k] : 0.f;
    ushort hi = f2bf(v);
    dhi[idx] = hi;
    dlo[idx] = f2bf(v - bf2f(hi));
}

// ---------------------------------------------------------------------------
// Bond K=6 matvec: out[MB][320] = bond[MB][6] @ w[6][300] (+bias), pad cols = 0
// ---------------------------------------------------------------------------
__global__ __launch_bounds__(256) void bondmm_k(
    const float* __restrict__ bf, const float* __restrict__ wmat,
    const float* __restrict__ bias, float* __restrict__ out)
{
    int idx = blockIdx.x * 256 + threadIdx.x;
    if (idx >= MB_ * 80) return;
    int row = idx / 80, c4 = idx - row * 80;
    float4 s = make_float4(0.f, 0.f, 0.f, 0.f);
    if (c4 < 75) {
        int col = c4 * 4;
        if (bias) s = *(const float4*)(bias + col);
        #pragma unroll
        for (int k = 0; k < 6; ++k) {
            float b = bf[(size_t)row * 6 + k];
            float4 wv = *(const float4*)(wmat + (size_t)k * H_ + col);
            s.x = fmaf(b, wv.x, s.x); s.y = fmaf(b, wv.y, s.y);
            s.z = fmaf(b, wv.z, s.z); s.w = fmaf(b, wv.w, s.w);
        }
    }
    *(float4*)(out + (size_t)row * NP_ + c4 * 4) = s;
}

// ---------------------------------------------------------------------------
// nei[ba,:] = sum_{n<nn} relu(hw[arow] + bwn[brow])   -> split bf16 out
// ---------------------------------------------------------------------------
__global__ __launch_bounds__(256) void agg_relu_k(
    const float* __restrict__ hw, const float* __restrict__ bwn,
    const int* __restrict__ ag, const int* __restrict__ bg,
    const int* __restrict__ num_nbs,
    ushort* __restrict__ neiH, ushort* __restrict__ neiL)
{
    int idx = blockIdx.x * 256 + threadIdx.x;
    if (idx >= MA_ * 80) return;
    int ba = idx / 80, c4 = idx - ba * 80;
    int nn = num_nbs[ba];
    const int* agp = ag + (size_t)ba * NB_ * 2;
    const int* bgp = bg + (size_t)ba * NB_ * 2;
    float4 s = make_float4(0.f, 0.f, 0.f, 0.f);
    for (int n = 0; n < nn; ++n) {
        int arow = agp[2*n] * A_    + agp[2*n+1];
        int brow = bgp[2*n] * BOND_ + bgp[2*n+1];
        float4 hv = *(const float4*)(hw  + (size_t)arow * NP_ + c4 * 4);
        float4 bv = *(const float4*)(bwn + (size_t)brow * NP_ + c4 * 4);
        s.x += fmaxf(hv.x + bv.x, 0.f); s.y += fmaxf(hv.y + bv.y, 0.f);
        s.z += fmaxf(hv.z + bv.z, 0.f); s.w += fmaxf(hv.w + bv.w, 0.f);
    }
    size_t o = (size_t)ba * NP_ + c4 * 4;
    ushort4 hi, lo;
    hi.x = f2bf(s.x); lo.x = f2bf(s.x - bf2f(hi.x));
    hi.y = f2bf(s.y); lo.y = f2bf(s.y - bf2f(hi.y));
    hi.z = f2bf(s.z); lo.z = f2bf(s.z - bf2f(hi.z));
    hi.w = f2bf(s.w); lo.w = f2bf(s.w - bf2f(hi.w));
    *(ushort4*)(neiH + o) = hi;
    *(ushort4*)(neiL + o) = lo;
}

// nei[ba,:] = sum_{n<nn} hw2[arow] * bw2[brow]   -> f32 out
__global__ __launch_bounds__(256) void agg_prod_k(
    const float* __restrict__ hw2, const float* __restrict__ bw2,
    const int* __restrict__ ag, const int* __restrict__ bg,
    const int* __restrict__ num_nbs, float* __restrict__ neiF)
{
    int idx = blockIdx.x * 256 + threadIdx.x;
    if (idx >= MA_ * 80) return;
    int ba = idx / 80, c4 = idx - ba * 80;
    int nn = num_nbs[ba];
    const int* agp = ag + (size_t)ba * NB_ * 2;
    const int* bgp = bg + (size_t)ba * NB_ * 2;
    float4 s = make_float4(0.f, 0.f, 0.f, 0.f);
    for (int n = 0; n < nn; ++n) {
        int arow = agp[2*n] * A_    + agp[2*n+1];
        int brow = bgp[2*n] * BOND_ + bgp[2*n+1];
        float4 hv = *(const float4*)(hw2 + (size_t)arow * NP_ + c4 * 4);
        float4 bv = *(const float4*)(bw2 + (size_t)brow * NP_ + c4 * 4);
        s.x = fmaf(hv.x, bv.x, s.x); s.y = fmaf(hv.y, bv.y, s.y);
        s.z = fmaf(hv.z, bv.z, s.z); s.w = fmaf(hv.w, bv.w, s.w);
    }
    *(float4*)(neiF + (size_t)ba * NP_ + c4 * 4) = s;
}

// ===========================================================================
extern "C" void kernel_launch(void* const* d_in, const int* in_sizes, int n_in,
                              void* d_out, int out_size, void* d_ws, size_t ws_size,
                              hipStream_t stream)
{
    const float* atom_feats = (const float*)d_in[0];
    const float* bond_feats = (const float*)d_in[1];
    const float* w_fc1      = (const float*)d_in[2];
    const float* w_nei      = (const float*)d_in[3];
    const float* b_nei      = (const float*)d_in[4];
    const float* w_atom     = (const float*)d_in[5];
    const float* b_atom     = (const float*)d_in[6];
    const float* w2a        = (const float*)d_in[7];
    const float* w2b        = (const float*)d_in[8];
    const float* w_fc2      = (const float*)d_in[9];
    const int*   atom_graph = (const int*)d_in[10];
    const int*   bond_graph = (const int*)d_in[11];
    const int*   num_nbs    = (const int*)d_in[12];
    const int*   n_atoms    = (const int*)d_in[13];
    float* out = (float*)d_out;
    (void)in_sizes; (void)n_in; (void)out_size; (void)ws_size;

    // workspace layout
    const size_t SZ_H16 = (size_t)MA_ * NP_ * 2;   // 16,384,000
    const size_t SZ_HF  = (size_t)MA_ * NP_ * 4;   // 32,768,000
    const size_t SZ_BWN = (size_t)MB_ * NP_ * 4;   // 36,044,800
    const size_t SZ_AF  = (size_t)MA_ * KP82 * 2;  //  4,915,200
    const size_t SZ_WT  = (size_t)NP_ * KP300 * 2; //    204,800
    const size_t SZ_WT1 = (size_t)NP_ * KP82 * 2;  //     61,440
    char* p = (char*)d_ws;
    ushort* hA_h = (ushort*)p; p += SZ_H16;
    ushort* hA_l = (ushort*)p; p += SZ_H16;
    ushort* hB_h = (ushort*)p; p += SZ_H16;
    ushort* hB_l = (ushort*)p; p += SZ_H16;
    ushort* nei_h = (ushort*)p; p += SZ_H16;
    ushort* nei_l = (ushort*)p; p += SZ_H16;
    float* hwF = (float*)p; p += SZ_HF;
    float* bwn = (float*)p; p += SZ_BWN;
    ushort* af_h = (ushort*)p; p += SZ_AF;
    ushort* af_l = (ushort*)p; p += SZ_AF;
    ushort* wfc1_h = (ushort*)p; p += SZ_WT1;
    ushort* wfc1_l = (ushort*)p; p += SZ_WT1;
    ushort* wn1_h  = (ushort*)p; p += SZ_WT;
    ushort* wn1_l  = (ushort*)p; p += SZ_WT;
    ushort* wa1_h  = (ushort*)p; p += SZ_WT;
    ushort* wa1_l  = (ushort*)p; p += SZ_WT;
    ushort* wa2_h  = (ushort*)p; p += SZ_WT;
    ushort* wa2_l  = (ushort*)p; p += SZ_WT;
    ushort* w2a_h  = (ushort*)p; p += SZ_WT;
    ushort* w2a_l  = (ushort*)p; p += SZ_WT;
    ushort* wfc2_h = (ushort*)p; p += SZ_WT;
    ushort* wfc2_l = (ushort*)p; p += SZ_WT;
    float* neiF = (float*)hB_h;   // alias: hB pair dead before agg_prod

    const dim3 blk(256);
    const dim3 gG(MA_ / 64);                 // 400 blocks
    const int  aggG  = (MA_ * 80 + 255) / 256;   // 8000
    const int  bondG = (MB_ * 80 + 255) / 256;   // 8800

    // weight conversions (transpose+split+pad)
    conv_af_k<<<(MA_*KP82+255)/256, blk, 0, stream>>>(atom_feats, af_h, af_l);
    conv_w_k<<<(NP_*KP82 +255)/256, blk, 0, stream>>>(w_fc1, AF_, KP82, wfc1_h, wfc1_l);
    conv_w_k<<<(NP_*KP300+255)/256, blk, 0, stream>>>(w_nei,              H_, KP300, wn1_h, wn1_l);
    conv_w_k<<<(NP_*KP300+255)/256, blk, 0, stream>>>(w_atom,             H_, KP300, wa1_h, wa1_l);
    conv_w_k<<<(NP_*KP300+255)/256, blk, 0, stream>>>(w_atom + (size_t)H_*H_, H_, KP300, wa2_h, wa2_l);
    conv_w_k<<<(NP_*KP300+255)/256, blk, 0, stream>>>(w2a,                H_, KP300, w2a_h, w2a_l);
    conv_w_k<<<(NP_*KP300+255)/256, blk, 0, stream>>>(w_fc2,              H_, KP300, wfc2_h, wfc2_l);

    // bwn = bond_feats @ w_nei[300:,:] + b_nei
    bondmm_k<<<bondG, blk, 0, stream>>>(bond_feats, w_nei + (size_t)H_*H_, b_nei, bwn);

    // h = relu(af @ w_fc1)  -> hA
    mgemm_k<false,false,true,0><<<gG, blk, 0, stream>>>(
        af_h, af_l, wfc1_h, wfc1_l, nullptr,nullptr,nullptr,nullptr, KP82,
        nullptr, nullptr, nullptr, hA_h, hA_l, nullptr);

    ushort* hc_h = hA_h; ushort* hc_l = hA_l;
    ushort* hn_h = hB_h; ushort* hn_l = hB_l;
    for (int it = 0; it < 2; ++it) {
        // hw = h @ w_nei[:300]
        mgemm_k<false,false,false,1><<<gG, blk, 0, stream>>>(
            hc_h, hc_l, wn1_h, wn1_l, nullptr,nullptr,nullptr,nullptr, KP300,
            nullptr, nullptr, nullptr, nullptr, nullptr, hwF);
        // nei = sum relu(gather(hw)+gather(bwn))
        agg_relu_k<<<aggG, blk, 0, stream>>>(hwF, bwn, atom_graph, bond_graph, num_nbs, nei_h, nei_l);
        // h_new = relu(h@wa1 + nei@wa2 + b_atom)
        mgemm_k<true,true,true,0><<<gG, blk, 0, stream>>>(
            hc_h, hc_l, wa1_h, wa1_l, nei_h, nei_l, wa2_h, wa2_l, KP300,
            b_atom, nullptr, nullptr, hn_h, hn_l, nullptr);
        ushort* t;
        t = hc_h; hc_h = hn_h; hn_h = t;
        t = hc_l; hc_l = hn_l; hn_l = t;
    }
    // after 2 iters: hc = hA pair; hB pair dead -> neiF alias is safe

    // bw2 = bond_feats @ w2b   (reuse bwn)
    bondmm_k<<<bondG, blk, 0, stream>>>(bond_feats, w2b, nullptr, bwn);
    // hw2 = h @ w2a
    mgemm_k<false,false,false,1><<<gG, blk, 0, stream>>>(
        hc_h, hc_l, w2a_h, w2a_l, nullptr,nullptr,nullptr,nullptr, KP300,
        nullptr, nullptr, nullptr, nullptr, nullptr, hwF);
    // neiF = sum gather(hw2)*gather(bw2)
    agg_prod_k<<<aggG, blk, 0, stream>>>(hwF, bwn, atom_graph, bond_graph, num_nbs, neiF);
    // out = (h @ w_fc2) * neiF, row-masked
    mgemm_k<false,false,false,2><<<gG, blk, 0, stream>>>(
        hc_h, hc_l, wfc2_h, wfc2_l, nullptr,nullptr,nullptr,nullptr, KP300,
        nullptr, neiF, n_atoms, nullptr, nullptr, out);
}